// Round 5
// baseline (280.367 us; speedup 1.0000x reference)
//
#include <hip/hip_runtime.h>
#include <math.h>

// YOLOv1 loss: S=7, B=2, C=1, BATCH=32768
// predictions: (BATCH, 7, 7, 11) fp32   targets: (BATCH, 7, 7, 6) fp32
// out: 5 fp32 scalars: total, coord/bs, conf_obj/bs, conf_noobj/bs, class/bs
//
// v5: single fused kernel. Four load mechanisms (strided direct, LDS-DMA,
// reg-staged coalesced, non-temporal) all pinned the partial at ~42-45us
// == the preceding 282.6MB re-poison fill's L2/L3 writeback drain time:
// the partial is SHADOWED by the drain (its reads contend with ~283MB of
// dirty-line writeback; FETCH showed half the stream still L2/L3-resident).
// Kernel-internal speed is therefore hidden; the only exposed serial work
// is the second launch (~2.5us exec + gap). This version fuses the final
// reduction via device-scope ticket: each block writes its float4 partial,
// __threadfence(), atomicAdd ticket; the last block re-reduces all
// partials and writes the 5 outputs. Counter zeroed by a 4B
// hipMemsetAsync (graph-capture-safe). Load structure = v1's empirical
// best: direct overlapping float4 loads, 2 cells/thread, no LDS staging.

#define PRED_C 11
#define TGT_C  6
#define TPB    256
#define LAMBDA_COORD 5.0f
#define LAMBDA_NOOBJ 0.5f
#define EPSV 1e-6f

// dword-aligned vectors (gfx950 global loads need only 4B alignment)
typedef float f4u __attribute__((ext_vector_type(4), aligned(4)));
typedef float f2u __attribute__((ext_vector_type(2), aligned(4)));

// fast sigmoid: |rel err| ~1e-6, far inside the absmax budget
__device__ __forceinline__ float fsig(float x) {
    return __builtin_amdgcn_rcpf(1.0f + __expf(-x));
}

// a = p[0..3], b = p[4..7], c = p[7..10], t4 = t[0..3], t2 = t[4..5]
// box0: x=a.x y=a.y w=a.z h=a.w conf=b.x
// box1: x=b.y y=b.z w=b.w h=c.y conf=c.z   class=c.w
__device__ __forceinline__ void cell_loss(f4u a, f4u b, f4u c, f4u t4, f2u t2,
                                          float& acc_coord, float& acc_cobj,
                                          float& acc_cnoobj, float& acc_cls)
{
    const float tx = t4.x, ty = t4.y, tw = t4.z, th = t4.w;
    const float tconf = t2.x, tcls = t2.y;
    const float obj   = (tconf == 1.0f) ? 1.0f : 0.0f;
    const float noobj = (tconf == 0.0f) ? 1.0f : 0.0f;

    const float t1x = tx - tw * 0.5f, t1y = ty - th * 0.5f;
    const float t2x = tx + tw * 0.5f, t2y = ty + th * 0.5f;
    const float tarea = tw * th;

    const float px[2] = { a.x, b.y };
    const float py[2] = { a.y, b.z };
    const float pw[2] = { a.z, b.w };
    const float ph[2] = { a.w, c.y };
    const float pf[2] = { b.x, c.z };

    float iou[2], sx[2], sy[2], aw[2], ah[2], scf[2];
    #pragma unroll
    for (int bb = 0; bb < 2; ++bb) {
        sx[bb]  = fsig(px[bb]);
        sy[bb]  = fsig(py[bb]);
        scf[bb] = fsig(pf[bb]);
        aw[bb]  = fabsf(pw[bb]);
        ah[bb]  = fabsf(ph[bb]);
        const float p1x = sx[bb] - aw[bb] * 0.5f, p1y = sy[bb] - ah[bb] * 0.5f;
        const float p2x = sx[bb] + aw[bb] * 0.5f, p2y = sy[bb] + ah[bb] * 0.5f;
        const float ix = fminf(p2x, t2x) - fmaxf(p1x, t1x);
        const float iy = fminf(p2y, t2y) - fmaxf(p1y, t1y);
        const float inter = fmaxf(ix, 0.0f) * fmaxf(iy, 0.0f);
        const float parea = aw[bb] * ah[bb];
        iou[bb] = inter * __builtin_amdgcn_rcpf(parea + tarea - inter + EPSV);
    }
    // jnp.argmax: first occurrence of max -> box1 only if strictly greater
    const int best = (iou[1] > iou[0]) ? 1 : 0;

    const float dx = sx[best] - tx;
    const float dy = sy[best] - ty;
    const float dw = __builtin_amdgcn_sqrtf(aw[best] + EPSV) -
                     __builtin_amdgcn_sqrtf(tw + EPSV);
    const float dh = __builtin_amdgcn_sqrtf(ah[best] + EPSV) -
                     __builtin_amdgcn_sqrtf(th + EPSV);
    acc_coord += LAMBDA_COORD * obj * ((dx * dx + dy * dy) + (dw * dw + dh * dh));

    const float sc = scf[best];
    acc_cobj += obj * (sc - tconf) * (sc - tconf);

    const float d0 = scf[0] - tconf;
    const float d1 = scf[1] - tconf;
    acc_cnoobj += LAMBDA_NOOBJ * noobj * (d0 * d0 + d1 * d1);

    const float pc = c.w;
    const float bce = fmaxf(pc, 0.0f) - pc * tcls +
                      __logf(1.0f + __expf(-fabsf(pc)));
    acc_cls += obj * bce;
}

__global__ __launch_bounds__(TPB) void yolo_fused_kernel(
    const float* __restrict__ pred,
    const float* __restrict__ tgt,
    float* __restrict__ partials,          // nblk float4s in d_ws
    unsigned int* __restrict__ counter,    // 1 uint after partials, pre-zeroed
    int nblk,
    float inv_bs,
    float* __restrict__ out)
{
    __shared__ float red[4][4];
    __shared__ int s_last;
    const int tid = threadIdx.x;
    const long long c0 = (long long)blockIdx.x * (TPB * 2) + tid;
    const long long c1 = c0 + TPB;

    // ---- issue all loads up front (deep MLP) ----
    const float* p0 = pred + c0 * PRED_C;
    const float* p1 = pred + c1 * PRED_C;
    const float* t0 = tgt  + c0 * TGT_C;
    const float* t1 = tgt  + c1 * TGT_C;

    const f4u a0 = *(const f4u*)(p0);
    const f4u b0 = *(const f4u*)(p0 + 4);
    const f4u cc0 = *(const f4u*)(p0 + 7);
    const f4u a1 = *(const f4u*)(p1);
    const f4u b1 = *(const f4u*)(p1 + 4);
    const f4u cc1 = *(const f4u*)(p1 + 7);
    const f4u t40 = *(const f4u*)(t0);
    const f2u t20 = *(const f2u*)(t0 + 4);
    const f4u t41 = *(const f4u*)(t1);
    const f2u t21 = *(const f2u*)(t1 + 4);

    float coord = 0.f, cobj = 0.f, cnoobj = 0.f, cls = 0.f;
    cell_loss(a0, b0, cc0, t40, t20, coord, cobj, cnoobj, cls);
    cell_loss(a1, b1, cc1, t41, t21, coord, cobj, cnoobj, cls);

    // ---- block reduction: wave shuffle (64-wide) -> cross-wave LDS ----
    #pragma unroll
    for (int off = 32; off >= 1; off >>= 1) {
        coord  += __shfl_down(coord, off);
        cobj   += __shfl_down(cobj, off);
        cnoobj += __shfl_down(cnoobj, off);
        cls    += __shfl_down(cls, off);
    }
    const int wave = tid >> 6;
    const int lane = tid & 63;
    if (lane == 0) {
        red[wave][0] = coord;
        red[wave][1] = cobj;
        red[wave][2] = cnoobj;
        red[wave][3] = cls;
    }
    __syncthreads();

    // ---- publish partial, take a ticket; last block finishes ----
    if (tid == 0) {
        float4 v;
        v.x = red[0][0] + red[1][0] + red[2][0] + red[3][0];
        v.y = red[0][1] + red[1][1] + red[2][1] + red[3][1];
        v.z = red[0][2] + red[1][2] + red[2][2] + red[3][2];
        v.w = red[0][3] + red[1][3] + red[2][3] + red[3][3];
        ((float4*)partials)[blockIdx.x] = v;
        __threadfence();                              // release partial
        const unsigned int old = atomicAdd(counter, 1u);
        s_last = (old == (unsigned int)(nblk - 1)) ? 1 : 0;
    }
    __syncthreads();
    if (s_last == 0) return;

    // ---- final reduction by the last block (exposed tail ~1us) ----
    __threadfence();                                  // acquire all partials
    float c = 0.f, co = 0.f, cn = 0.f, cl = 0.f;
    for (int i = tid; i < nblk; i += TPB) {
        const volatile float* vp = partials + (size_t)i * 4;
        c  += vp[0];
        co += vp[1];
        cn += vp[2];
        cl += vp[3];
    }
    #pragma unroll
    for (int off = 32; off >= 1; off >>= 1) {
        c  += __shfl_down(c, off);
        co += __shfl_down(co, off);
        cn += __shfl_down(cn, off);
        cl += __shfl_down(cl, off);
    }
    if (lane == 0) {
        red[wave][0] = c;
        red[wave][1] = co;
        red[wave][2] = cn;
        red[wave][3] = cl;
    }
    __syncthreads();
    if (tid == 0) {
        float sc = 0.f, sco = 0.f, scn = 0.f, scl = 0.f;
        #pragma unroll
        for (int w = 0; w < 4; ++w) {
            sc  += red[w][0];
            sco += red[w][1];
            scn += red[w][2];
            scl += red[w][3];
        }
        out[0] = (sc + sco + scn + scl) * inv_bs;
        out[1] = sc  * inv_bs;
        out[2] = sco * inv_bs;
        out[3] = scn * inv_bs;
        out[4] = scl * inv_bs;
    }
}

extern "C" void kernel_launch(void* const* d_in, const int* in_sizes, int n_in,
                              void* d_out, int out_size, void* d_ws, size_t ws_size,
                              hipStream_t stream) {
    const float* pred = (const float*)d_in[0];
    const float* tgt  = (const float*)d_in[1];
    float* out = (float*)d_out;
    float* partials = (float*)d_ws;

    const long long batch = (long long)in_sizes[0] / (7 * 7 * PRED_C);
    const long long cells = batch * 49;              // 1,605,632
    const int nblk = (int)(cells / (TPB * 2));       // 3136 exact

    unsigned int* counter =
        (unsigned int*)((char*)d_ws + (size_t)nblk * 4 * sizeof(float));

    hipMemsetAsync(counter, 0, sizeof(unsigned int), stream);
    yolo_fused_kernel<<<nblk, TPB, 0, stream>>>(pred, tgt, partials, counter,
                                                nblk, 1.0f / (float)batch, out);
}

// Round 6
// 130.800 us; speedup vs baseline: 2.1435x; 2.1435x over previous
//
#include <hip/hip_runtime.h>
#include <math.h>

// YOLOv1 loss: S=7, B=2, C=1, BATCH=32768
// predictions: (BATCH, 7, 7, 11) fp32   targets: (BATCH, 7, 7, 6) fp32
// out: 5 fp32 scalars: total, coord/bs, conf_obj/bs, conf_noobj/bs, class/bs
//
// v6 == v1 (verified best, 129.8-130.7us): pure-streaming stage-1, direct
// dword-aligned vector loads (pred cell = float4 @ +0,+4,+7 overlapping;
// tgt = float4+float2), 2 cells/thread, one float4 partial per block.
// Stage-2: one 1024-thread block reduces 3136 partials.
//
// Session findings (why this structure is final):
// - Stage-1 is pinned at ~42-45us (2.6 TB/s read) by a per-CU read cap
//   (~4.2 B/cy/CU, MSHR x latency): four mechanisms (strided direct,
//   global_load_lds DMA, reg-staged coalesced dwordx4, non-temporal)
//   all land identical. Copy-bench read component (~3.1 TB/s) bounds
//   upside to ~7us total.
// - The timed region carries 2x42.5us harness re-poison fills (282.6 MB
//   each) -- untouchable from kernel source.
// - Tail fusion via device-scope ticket+__threadfence REGRESSED 4x
//   (v5: 183us in-kernel): cross-XCD release of ordinary stores forces
//   L2 writeback per block. Two-kernel tail (~4us) is the right shape.

#define PRED_C 11
#define TGT_C  6
#define TPB    256
#define CELLS_PER_THREAD 2
#define LAMBDA_COORD 5.0f
#define LAMBDA_NOOBJ 0.5f
#define EPSV 1e-6f

// dword-aligned float4 (gfx950 global loads require only 4B alignment)
typedef float f4u __attribute__((ext_vector_type(4), aligned(4)));
typedef float f2u __attribute__((ext_vector_type(2), aligned(4)));

// fast sigmoid: |rel err| ~1e-6, far inside the absmax budget
__device__ __forceinline__ float fsig(float x) {
    return __builtin_amdgcn_rcpf(1.0f + __expf(-x));
}

// a = p[0..3], b = p[4..7], c = p[7..10], t4 = t[0..3], t2 = t[4..5]
__device__ __forceinline__ void cell_loss(f4u a, f4u b, f4u c, f4u t4, f2u t2,
                                          float& acc_coord, float& acc_cobj,
                                          float& acc_cnoobj, float& acc_cls)
{
    const float tx = t4.x, ty = t4.y, tw = t4.z, th = t4.w;
    const float tconf = t2.x, tcls = t2.y;
    const float obj   = (tconf == 1.0f) ? 1.0f : 0.0f;
    const float noobj = (tconf == 0.0f) ? 1.0f : 0.0f;

    const float t1x = tx - tw * 0.5f, t1y = ty - th * 0.5f;
    const float t2x = tx + tw * 0.5f, t2y = ty + th * 0.5f;
    const float tarea = tw * th;

    // box0: x=a.x y=a.y w=a.z h=a.w conf=b.x
    // box1: x=b.y y=b.z w=b.w h=c.y conf=c.z   class=c.w
    const float px[2] = { a.x, b.y };
    const float py[2] = { a.y, b.z };
    const float pw[2] = { a.z, b.w };
    const float ph[2] = { a.w, c.y };
    const float pf[2] = { b.x, c.z };

    float iou[2], sx[2], sy[2], aw[2], ah[2], scf[2];
    #pragma unroll
    for (int bb = 0; bb < 2; ++bb) {
        sx[bb]  = fsig(px[bb]);
        sy[bb]  = fsig(py[bb]);
        scf[bb] = fsig(pf[bb]);
        aw[bb]  = fabsf(pw[bb]);
        ah[bb]  = fabsf(ph[bb]);
        const float p1x = sx[bb] - aw[bb] * 0.5f, p1y = sy[bb] - ah[bb] * 0.5f;
        const float p2x = sx[bb] + aw[bb] * 0.5f, p2y = sy[bb] + ah[bb] * 0.5f;
        const float ix = fminf(p2x, t2x) - fmaxf(p1x, t1x);
        const float iy = fminf(p2y, t2y) - fmaxf(p1y, t1y);
        const float inter = fmaxf(ix, 0.0f) * fmaxf(iy, 0.0f);
        const float parea = aw[bb] * ah[bb];
        iou[bb] = inter * __builtin_amdgcn_rcpf(parea + tarea - inter + EPSV);
    }
    // jnp.argmax: first occurrence of max -> box1 only if strictly greater
    const int best = (iou[1] > iou[0]) ? 1 : 0;

    const float dx = sx[best] - tx;
    const float dy = sy[best] - ty;
    const float dw = __builtin_amdgcn_sqrtf(aw[best] + EPSV) -
                     __builtin_amdgcn_sqrtf(tw + EPSV);
    const float dh = __builtin_amdgcn_sqrtf(ah[best] + EPSV) -
                     __builtin_amdgcn_sqrtf(th + EPSV);
    acc_coord += LAMBDA_COORD * obj * ((dx * dx + dy * dy) + (dw * dw + dh * dh));

    const float sc = scf[best];
    acc_cobj += obj * (sc - tconf) * (sc - tconf);

    const float d0 = scf[0] - tconf;
    const float d1 = scf[1] - tconf;
    acc_cnoobj += LAMBDA_NOOBJ * noobj * (d0 * d0 + d1 * d1);

    const float pc = c.w;
    const float bce = fmaxf(pc, 0.0f) - pc * tcls +
                      __logf(1.0f + __expf(-fabsf(pc)));
    acc_cls += obj * bce;
}

__global__ __launch_bounds__(TPB) void yolo_partial_kernel(
    const float* __restrict__ pred,
    const float* __restrict__ tgt,
    float* __restrict__ partials)   // gridDim.x float4s
{
    __shared__ float red[4][4];
    const int tid = threadIdx.x;
    const long long c0 = (long long)blockIdx.x * (TPB * CELLS_PER_THREAD) + tid;
    const long long c1 = c0 + TPB;

    // ---- issue all loads up front (deep MLP) ----
    const float* p0 = pred + c0 * PRED_C;
    const float* p1 = pred + c1 * PRED_C;
    const float* t0 = tgt  + c0 * TGT_C;
    const float* t1 = tgt  + c1 * TGT_C;

    const f4u a0 = *(const f4u*)(p0);
    const f4u b0 = *(const f4u*)(p0 + 4);
    const f4u cc0 = *(const f4u*)(p0 + 7);
    const f4u a1 = *(const f4u*)(p1);
    const f4u b1 = *(const f4u*)(p1 + 4);
    const f4u cc1 = *(const f4u*)(p1 + 7);
    const f4u t40 = *(const f4u*)(t0);
    const f2u t20 = *(const f2u*)(t0 + 4);
    const f4u t41 = *(const f4u*)(t1);
    const f2u t21 = *(const f2u*)(t1 + 4);

    float coord = 0.f, cobj = 0.f, cnoobj = 0.f, cls = 0.f;
    cell_loss(a0, b0, cc0, t40, t20, coord, cobj, cnoobj, cls);
    cell_loss(a1, b1, cc1, t41, t21, coord, cobj, cnoobj, cls);

    // ---- reduction: wave shuffle (64-wide) -> cross-wave LDS -> float4 store
    #pragma unroll
    for (int off = 32; off >= 1; off >>= 1) {
        coord  += __shfl_down(coord, off);
        cobj   += __shfl_down(cobj, off);
        cnoobj += __shfl_down(cnoobj, off);
        cls    += __shfl_down(cls, off);
    }
    const int wave = tid >> 6;
    const int lane = tid & 63;
    if (lane == 0) {
        red[wave][0] = coord;
        red[wave][1] = cobj;
        red[wave][2] = cnoobj;
        red[wave][3] = cls;
    }
    __syncthreads();
    if (tid == 0) {
        float4 v;
        v.x = red[0][0] + red[1][0] + red[2][0] + red[3][0];
        v.y = red[0][1] + red[1][1] + red[2][1] + red[3][1];
        v.z = red[0][2] + red[1][2] + red[2][2] + red[3][2];
        v.w = red[0][3] + red[1][3] + red[2][3] + red[3][3];
        ((float4*)partials)[blockIdx.x] = v;
    }
}

__global__ __launch_bounds__(1024) void yolo_final_kernel(
    const float* __restrict__ partials,
    float* __restrict__ out,
    int nblk,
    float inv_bs)
{
    __shared__ float red[16][4];
    const int tid = threadIdx.x;

    float c = 0.f, co = 0.f, cn = 0.f, cl = 0.f;
    for (int i = tid; i < nblk; i += 1024) {
        const float4 v = ((const float4*)partials)[i];
        c += v.x; co += v.y; cn += v.z; cl += v.w;
    }
    #pragma unroll
    for (int off = 32; off >= 1; off >>= 1) {
        c  += __shfl_down(c, off);
        co += __shfl_down(co, off);
        cn += __shfl_down(cn, off);
        cl += __shfl_down(cl, off);
    }
    const int wave = tid >> 6;
    const int lane = tid & 63;
    if (lane == 0) {
        red[wave][0] = c;
        red[wave][1] = co;
        red[wave][2] = cn;
        red[wave][3] = cl;
    }
    __syncthreads();
    if (tid == 0) {
        float sc = 0.f, sco = 0.f, scn = 0.f, scl = 0.f;
        #pragma unroll
        for (int w = 0; w < 16; ++w) {
            sc  += red[w][0];
            sco += red[w][1];
            scn += red[w][2];
            scl += red[w][3];
        }
        out[0] = (sc + sco + scn + scl) * inv_bs;
        out[1] = sc  * inv_bs;
        out[2] = sco * inv_bs;
        out[3] = scn * inv_bs;
        out[4] = scl * inv_bs;
    }
}

extern "C" void kernel_launch(void* const* d_in, const int* in_sizes, int n_in,
                              void* d_out, int out_size, void* d_ws, size_t ws_size,
                              hipStream_t stream) {
    const float* pred = (const float*)d_in[0];
    const float* tgt  = (const float*)d_in[1];
    float* out = (float*)d_out;
    float* partials = (float*)d_ws;

    const long long batch = (long long)in_sizes[0] / (7 * 7 * PRED_C);
    const long long cells = batch * 49;                       // 1,605,632
    const int nblk = (int)(cells / (TPB * CELLS_PER_THREAD)); // 3136 exact

    yolo_partial_kernel<<<nblk, TPB, 0, stream>>>(pred, tgt, partials);
    yolo_final_kernel<<<1, 1024, 0, stream>>>(partials, out, nblk,
                                              1.0f / (float)batch);
}